// Round 1
// baseline (3360.283 us; speedup 1.0000x reference)
//
#include <hip/hip_runtime.h>
#include <cstdint>
#include <cstddef>

#define TM 128
#define TN 128
#define TK 32

// ---------------------------------------------------------------------------
// Weight transpose: w (O, I, 4) -> wt (4, I, O)   [coalesced writes, 16B reads]
// ---------------------------------------------------------------------------
__global__ void transpose_convw(const float* __restrict__ w, float* __restrict__ wt,
                                int I, int O) {
    int o = blockIdx.x * 256 + threadIdx.x;
    int i = blockIdx.y;
    if (o >= O) return;
    float4 v = *reinterpret_cast<const float4*>(&w[((size_t)o * I + i) * 4]);
    size_t plane = (size_t)I * O;
    size_t base = (size_t)i * O + o;
    wt[base]             = v.x;
    wt[plane + base]     = v.y;
    wt[2 * plane + base] = v.z;
    wt[3 * plane + base] = v.w;
}

// ---------------------------------------------------------------------------
// Generic 2D transpose: in (R, C) -> out (C, R).  Grid: (C/32, R/32), 256 thr.
// ---------------------------------------------------------------------------
__global__ void transpose2d(const float* __restrict__ in, float* __restrict__ out,
                            int R, int C) {
    __shared__ float tile[32][33];
    int c0 = blockIdx.x * 32, r0 = blockIdx.y * 32;
    int tx = threadIdx.x & 31, ty = threadIdx.x >> 5;
#pragma unroll
    for (int q = 0; q < 4; q++) {
        int r = ty + q * 8;
        tile[r][tx] = in[(size_t)(r0 + r) * C + (c0 + tx)];
    }
    __syncthreads();
#pragma unroll
    for (int q = 0; q < 4; q++) {
        int r = ty + q * 8;
        out[(size_t)(c0 + r) * R + (r0 + tx)] = tile[tx][r];
    }
}

// ---------------------------------------------------------------------------
// Codebook row norms: one wave per row (256 cols = 64 lanes x float4)
// ---------------------------------------------------------------------------
__global__ void cnorm_kernel(const float* __restrict__ cb, float* __restrict__ cn) {
    int w = threadIdx.x >> 6, lane = threadIdx.x & 63;
    int row = blockIdx.x * 4 + w;
    float4 v = *reinterpret_cast<const float4*>(&cb[(size_t)row * 256 + lane * 4]);
    float s = v.x * v.x + v.y * v.y + v.z * v.z + v.w * v.w;
#pragma unroll
    for (int off = 32; off; off >>= 1) s += __shfl_xor(s, off);
    if (lane == 0) cn[row] = s;
}

// ---------------------------------------------------------------------------
// Conv1d(k=4, s=2, p=1) as GEMM:  out[m, o] = sum_{k,i} x[b, 2t-1+k, i] * wt[k,i,o]
// m = b*1024 + t,  M = 8192.  A-tile gathered from x, B-tile = wt row-major.
// ---------------------------------------------------------------------------
__global__ __launch_bounds__(256)
void conv_gemm(const float* __restrict__ x, const float* __restrict__ wt,
               const float* __restrict__ bias, float* __restrict__ out,
               int I, int O) {
    __shared__ float As[TK][TM + 4];
    __shared__ float Bs[TK][TN];
    const int tid = threadIdx.x;
    const int tx = tid & 15, ty = tid >> 4;
    const int m0 = blockIdx.x * TM;
    const int n0 = blockIdx.y * TN;
    const int b  = m0 >> 10;          // TM divides 1024
    const int t0 = m0 & 1023;
    const float* xb = x + (size_t)b * 2048 * I;
    const int KD = I * 4;

    float acc[8][8];
#pragma unroll
    for (int i = 0; i < 8; i++)
#pragma unroll
        for (int j = 0; j < 8; j++) acc[i][j] = 0.f;

    for (int kt = 0; kt < KD; kt += TK) {
        const int kcv = kt / I;               // conv tap (tile never straddles taps)
        const int i0  = kt - kcv * I;
        const int sb  = 2 * t0 - 1 + kcv;
        // ---- A tile (gather, zero-pad edges): rows m, cols i0..i0+31
#pragma unroll
        for (int p = 0; p < 4; p++) {
            int g = tid + p * 256;
            int r = g >> 3, c4 = (g & 7) << 2;
            int s = sb + 2 * r;
            float4 v = make_float4(0.f, 0.f, 0.f, 0.f);
            if (s >= 0 && s < 2048)
                v = *reinterpret_cast<const float4*>(&xb[(size_t)s * I + i0 + c4]);
            As[c4 + 0][r] = v.x; As[c4 + 1][r] = v.y;
            As[c4 + 2][r] = v.z; As[c4 + 3][r] = v.w;
        }
        // ---- B tile: wt rows kt..kt+31, cols n0..n0+127 (coalesced)
#pragma unroll
        for (int p = 0; p < 4; p++) {
            int g = tid + p * 256;
            int kk = g >> 5, c4 = (g & 31) << 2;
            *reinterpret_cast<float4*>(&Bs[kk][c4]) =
                *reinterpret_cast<const float4*>(&wt[(size_t)(kt + kk) * O + n0 + c4]);
        }
        __syncthreads();
#pragma unroll
        for (int kk = 0; kk < TK; kk++) {
            float a[8], bf[8];
            *reinterpret_cast<float4*>(&a[0])  = *reinterpret_cast<const float4*>(&As[kk][ty * 4]);
            *reinterpret_cast<float4*>(&a[4])  = *reinterpret_cast<const float4*>(&As[kk][64 + ty * 4]);
            *reinterpret_cast<float4*>(&bf[0]) = *reinterpret_cast<const float4*>(&Bs[kk][tx * 4]);
            *reinterpret_cast<float4*>(&bf[4]) = *reinterpret_cast<const float4*>(&Bs[kk][64 + tx * 4]);
#pragma unroll
            for (int i = 0; i < 8; i++)
#pragma unroll
                for (int j = 0; j < 8; j++)
                    acc[i][j] = fmaf(a[i], bf[j], acc[i][j]);
        }
        __syncthreads();
    }
#pragma unroll
    for (int i = 0; i < 8; i++) {
        int row = m0 + ((i < 4) ? (ty * 4 + i) : (64 + ty * 4 + i - 4));
#pragma unroll
        for (int h = 0; h < 2; h++) {
            int col = n0 + h * 64 + tx * 4;
            float4 bv = *reinterpret_cast<const float4*>(&bias[col]);
            float4 o;
            o.x = acc[i][h * 4 + 0] + bv.x;
            o.y = acc[i][h * 4 + 1] + bv.y;
            o.z = acc[i][h * 4 + 2] + bv.z;
            o.w = acc[i][h * 4 + 3] + bv.w;
            *reinterpret_cast<float4*>(&out[(size_t)row * O + col]) = o;
        }
    }
}

// ---------------------------------------------------------------------------
// Projection: z_e[m, d] = sum_c concat[m, c] * wtP[c, d] + proj_b[d]
// concat segments: [0,1280)=convA, [1280,2304)=convB, [2304,3328)=muq
// ---------------------------------------------------------------------------
__global__ __launch_bounds__(256)
void proj_gemm(const float* __restrict__ cA, const float* __restrict__ cB,
               const float* __restrict__ mu, const float* __restrict__ wt,
               const float* __restrict__ bias, float* __restrict__ out) {
    __shared__ float As[TK][TM + 4];
    __shared__ float Bs[TK][TN];
    const int tid = threadIdx.x;
    const int tx = tid & 15, ty = tid >> 4;
    const int m0 = blockIdx.x * TM;
    const int n0 = blockIdx.y * TN;
    const int O = 256;

    float acc[8][8];
#pragma unroll
    for (int i = 0; i < 8; i++)
#pragma unroll
        for (int j = 0; j < 8; j++) acc[i][j] = 0.f;

    for (int kt = 0; kt < 3328; kt += TK) {
        const float* ap; int astr, coff;
        if (kt < 1280)      { ap = cA; astr = 1280; coff = kt; }
        else if (kt < 2304) { ap = cB; astr = 1024; coff = kt - 1280; }
        else                { ap = mu; astr = 1024; coff = kt - 2304; }
#pragma unroll
        for (int p = 0; p < 4; p++) {
            int g = tid + p * 256;
            int r = g >> 3, c4 = (g & 7) << 2;
            float4 v = *reinterpret_cast<const float4*>(&ap[(size_t)(m0 + r) * astr + coff + c4]);
            As[c4 + 0][r] = v.x; As[c4 + 1][r] = v.y;
            As[c4 + 2][r] = v.z; As[c4 + 3][r] = v.w;
        }
#pragma unroll
        for (int p = 0; p < 4; p++) {
            int g = tid + p * 256;
            int kk = g >> 5, c4 = (g & 31) << 2;
            *reinterpret_cast<float4*>(&Bs[kk][c4]) =
                *reinterpret_cast<const float4*>(&wt[(size_t)(kt + kk) * O + n0 + c4]);
        }
        __syncthreads();
#pragma unroll
        for (int kk = 0; kk < TK; kk++) {
            float a[8], bf[8];
            *reinterpret_cast<float4*>(&a[0])  = *reinterpret_cast<const float4*>(&As[kk][ty * 4]);
            *reinterpret_cast<float4*>(&a[4])  = *reinterpret_cast<const float4*>(&As[kk][64 + ty * 4]);
            *reinterpret_cast<float4*>(&bf[0]) = *reinterpret_cast<const float4*>(&Bs[kk][tx * 4]);
            *reinterpret_cast<float4*>(&bf[4]) = *reinterpret_cast<const float4*>(&Bs[kk][64 + tx * 4]);
#pragma unroll
            for (int i = 0; i < 8; i++)
#pragma unroll
                for (int j = 0; j < 8; j++)
                    acc[i][j] = fmaf(a[i], bf[j], acc[i][j]);
        }
        __syncthreads();
    }
#pragma unroll
    for (int i = 0; i < 8; i++) {
        int row = m0 + ((i < 4) ? (ty * 4 + i) : (64 + ty * 4 + i - 4));
#pragma unroll
        for (int h = 0; h < 2; h++) {
            int col = n0 + h * 64 + tx * 4;
            float4 bv = *reinterpret_cast<const float4*>(&bias[col]);
            float4 o;
            o.x = acc[i][h * 4 + 0] + bv.x;
            o.y = acc[i][h * 4 + 1] + bv.y;
            o.z = acc[i][h * 4 + 2] + bv.z;
            o.w = acc[i][h * 4 + 3] + bv.w;
            *reinterpret_cast<float4*>(&out[(size_t)row * 256 + col]) = o;
        }
    }
}

// ---------------------------------------------------------------------------
// VQ pass 1: per (128-row, 128-code) tile, dot = z . c; criterion
// d = |c|^2 - 2 dot (row-constant |z|^2 dropped; compared in f64).
// Writes per-(row, code-chunk) partial argmin.
// ---------------------------------------------------------------------------
__global__ __launch_bounds__(256)
void vq_gemm(const float* __restrict__ z, const float* __restrict__ cbT,
             const float* __restrict__ cn, double* __restrict__ pmin,
             int* __restrict__ pidx) {
    __shared__ __align__(16) char smem[(TK * (TM + 4) + TK * TN) * 4];
    float (*As)[TM + 4] = reinterpret_cast<float (*)[TM + 4]>(smem);
    float (*Bs)[TN]     = reinterpret_cast<float (*)[TN]>(smem + TK * (TM + 4) * 4);
    const int tid = threadIdx.x;
    const int tx = tid & 15, ty = tid >> 4;
    const int m0 = blockIdx.x * TM;
    const int n0 = blockIdx.y * TN;

    float acc[8][8];
#pragma unroll
    for (int i = 0; i < 8; i++)
#pragma unroll
        for (int j = 0; j < 8; j++) acc[i][j] = 0.f;

    for (int kt = 0; kt < 256; kt += TK) {
#pragma unroll
        for (int p = 0; p < 4; p++) {
            int g = tid + p * 256;
            int r = g >> 3, c4 = (g & 7) << 2;
            float4 v = *reinterpret_cast<const float4*>(&z[(size_t)(m0 + r) * 256 + kt + c4]);
            As[c4 + 0][r] = v.x; As[c4 + 1][r] = v.y;
            As[c4 + 2][r] = v.z; As[c4 + 3][r] = v.w;
        }
#pragma unroll
        for (int p = 0; p < 4; p++) {
            int g = tid + p * 256;
            int kk = g >> 5, c4 = (g & 31) << 2;
            *reinterpret_cast<float4*>(&Bs[kk][c4]) =
                *reinterpret_cast<const float4*>(&cbT[(size_t)(kt + kk) * 8192 + n0 + c4]);
        }
        __syncthreads();
#pragma unroll
        for (int kk = 0; kk < TK; kk++) {
            float a[8], bf[8];
            *reinterpret_cast<float4*>(&a[0])  = *reinterpret_cast<const float4*>(&As[kk][ty * 4]);
            *reinterpret_cast<float4*>(&a[4])  = *reinterpret_cast<const float4*>(&As[kk][64 + ty * 4]);
            *reinterpret_cast<float4*>(&bf[0]) = *reinterpret_cast<const float4*>(&Bs[kk][tx * 4]);
            *reinterpret_cast<float4*>(&bf[4]) = *reinterpret_cast<const float4*>(&Bs[kk][64 + tx * 4]);
#pragma unroll
            for (int i = 0; i < 8; i++)
#pragma unroll
                for (int j = 0; j < 8; j++)
                    acc[i][j] = fmaf(a[i], bf[j], acc[i][j]);
        }
        __syncthreads();
    }
    // ---- epilogue: per-row partial argmin (smem reused; last sync above)
    double (*red_d)[16] = reinterpret_cast<double (*)[16]>(smem);
    int    (*red_n)[16] = reinterpret_cast<int    (*)[16]>(smem + 128 * 16 * 8);
#pragma unroll
    for (int i = 0; i < 8; i++) {
        int rl = (i < 4) ? (ty * 4 + i) : (64 + ty * 4 + i - 4);
        double best = 1e300; int bestn = 0x7fffffff;
#pragma unroll
        for (int j = 0; j < 8; j++) {
            int gn = n0 + ((j < 4) ? (tx * 4 + j) : (64 + tx * 4 + j - 4));
            double d = (double)cn[gn] - 2.0 * (double)acc[i][j];
            if (d < best || (d == best && gn < bestn)) { best = d; bestn = gn; }
        }
        red_d[rl][tx] = best; red_n[rl][tx] = bestn;
    }
    __syncthreads();
    if (tid < 128) {
        double best = red_d[tid][0]; int bestn = red_n[tid][0];
        for (int xk = 1; xk < 16; xk++) {
            double d = red_d[tid][xk]; int n2 = red_n[tid][xk];
            if (d < best || (d == best && n2 < bestn)) { best = d; bestn = n2; }
        }
        size_t idx = (size_t)(m0 + tid) * 64 + blockIdx.y;
        pmin[idx] = best; pidx[idx] = bestn;
    }
}

// ---------------------------------------------------------------------------
// VQ pass 2: final argmin over 64 chunks (one wave per row), gather z_q,
// codes (as float), per-row commit partial (f64, deterministic).
// ---------------------------------------------------------------------------
__global__ void vq_finalize(const double* __restrict__ pmin, const int* __restrict__ pidx,
                            const float* __restrict__ z, const float* __restrict__ cb,
                            float* __restrict__ out, double* __restrict__ cpart) {
    int w = threadIdx.x >> 6, lane = threadIdx.x & 63;
    int m = blockIdx.x * 4 + w;
    double d = pmin[(size_t)m * 64 + lane];
    int n = pidx[(size_t)m * 64 + lane];
#pragma unroll
    for (int off = 32; off; off >>= 1) {
        double d2 = __shfl_xor(d, off);
        int n2 = __shfl_xor(n, off);
        if (d2 < d || (d2 == d && n2 < n)) { d = d2; n = n2; }
    }
    float4 cv = *reinterpret_cast<const float4*>(&cb[(size_t)n * 256 + lane * 4]);
    float4 zv = *reinterpret_cast<const float4*>(&z[(size_t)m * 256 + lane * 4]);
    *reinterpret_cast<float4*>(&out[(size_t)m * 256 + lane * 4]) = cv;
    float dx = zv.x - cv.x, dy = zv.y - cv.y, dz = zv.z - cv.z, dw = zv.w - cv.w;
    double s = (double)(dx * dx) + (double)(dy * dy) + (double)(dz * dz) + (double)(dw * dw);
#pragma unroll
    for (int off = 32; off; off >>= 1) s += __shfl_xor(s, off);
    if (lane == 0) {
        out[2097152 + m] = (float)n;   // codes as float (f32 output buffer)
        cpart[m] = s;
    }
}

__global__ void vq_reduce(const double* __restrict__ cpart, float* __restrict__ out) {
    __shared__ double sm[256];
    double s = 0.0;
    for (int i = threadIdx.x; i < 8192; i += 256) s += cpart[i];
    sm[threadIdx.x] = s;
    __syncthreads();
    for (int off = 128; off; off >>= 1) {
        if ((int)threadIdx.x < off) sm[threadIdx.x] += sm[threadIdx.x + off];
        __syncthreads();
    }
    if (threadIdx.x == 0) out[2105344] = (float)(sm[0] / 2097152.0);
}

// ---------------------------------------------------------------------------
extern "C" void kernel_launch(void* const* d_in, const int* in_sizes, int n_in,
                              void* d_out, int out_size, void* d_ws, size_t ws_size,
                              hipStream_t stream) {
    (void)in_sizes; (void)n_in; (void)out_size; (void)ws_size;
    const float* whisper   = (const float*)d_in[0];
    const float* wavlm     = (const float*)d_in[1];
    const float* muq       = (const float*)d_in[2];
    const float* w_conv_w  = (const float*)d_in[3];
    const float* w_conv_b  = (const float*)d_in[4];
    const float* wl_conv_w = (const float*)d_in[5];
    const float* wl_conv_b = (const float*)d_in[6];
    const float* proj_w    = (const float*)d_in[7];
    const float* proj_b    = (const float*)d_in[8];
    const float* codebook  = (const float*)d_in[9];
    float* out = (float*)d_out;
    float* ws  = (float*)d_ws;

    // workspace layout (floats); total ~138.4 MB
    float* WtW   = ws;                       // 4*1280*1280
    float* WtWL  = WtW   + 6553600;          // 4*1024*1024
    float* WtP   = WtWL  + 4194304;          // 3328*256
    float* cbT   = WtP   + 851968;           // 256*8192
    float* cnorm = cbT   + 2097152;          // 8192
    float* convA = cnorm + 8192;             // 8192*1280
    float* convB = convA + 10485760;         // 8192*1024
    float* z_e   = convB + 8388608;          // 8192*256
    double* pmin = (double*)(z_e + 2097152); // 8192*64 doubles
    int*    pidx = (int*)(pmin + 524288);    // 8192*64 ints
    double* cpart= (double*)(pidx + 524288); // 8192 doubles

    transpose_convw<<<dim3(5, 1280), 256, 0, stream>>>(w_conv_w, WtW, 1280, 1280);
    transpose_convw<<<dim3(4, 1024), 256, 0, stream>>>(wl_conv_w, WtWL, 1024, 1024);
    transpose2d<<<dim3(104, 8), 256, 0, stream>>>(proj_w, WtP, 256, 3328);
    transpose2d<<<dim3(8, 256), 256, 0, stream>>>(codebook, cbT, 8192, 256);
    cnorm_kernel<<<2048, 256, 0, stream>>>(codebook, cnorm);

    conv_gemm<<<dim3(64, 10), 256, 0, stream>>>(whisper, WtW, w_conv_b, convA, 1280, 1280);
    conv_gemm<<<dim3(64, 8), 256, 0, stream>>>(wavlm, WtWL, wl_conv_b, convB, 1024, 1024);
    proj_gemm<<<dim3(64, 2), 256, 0, stream>>>(convA, convB, muq, WtP, proj_b, z_e);

    vq_gemm<<<dim3(64, 64), 256, 0, stream>>>(z_e, cbT, cnorm, pmin, pidx);
    vq_finalize<<<2048, 256, 0, stream>>>(pmin, pidx, z_e, codebook, out, cpart);
    vq_reduce<<<1, 256, 0, stream>>>(cpart, out);
}

// Round 2
// 2272.795 us; speedup vs baseline: 1.4785x; 1.4785x over previous
//
#include <hip/hip_runtime.h>
#include <cstdint>
#include <cstddef>

#define TM 128
#define TN 128
#define TK 32

typedef unsigned short u16;
typedef __attribute__((ext_vector_type(8))) short bf16x8;
typedef __attribute__((ext_vector_type(4))) float f32x4;
typedef unsigned int u32;
typedef __attribute__((address_space(1))) const u32 gu32;
typedef __attribute__((address_space(3))) u32 lu32;

__device__ __forceinline__ void gload_lds16(const void* g, void* l) {
    __builtin_amdgcn_global_load_lds((gu32*)g, (lu32*)l, 16, 0, 0);
}

__device__ __forceinline__ u16 f2bf(float v) {
    u32 u = __float_as_uint(v);
    return (u16)((u + 0x7fffu + ((u >> 16) & 1u)) >> 16);
}
__device__ __forceinline__ float bf2f(u16 h) { return __uint_as_float(((u32)h) << 16); }

// ---------------------------------------------------------------------------
// Weight prep: w (O, I, 4) f32 -> 3 bf16 planes, each (O, 4*I) with
// plane[o][kcv*I + i] = split_p(w[o][i][kcv]).  (B^T layout for MFMA: [n][k])
// ---------------------------------------------------------------------------
__global__ void split_weightT(const float* __restrict__ w, u16* __restrict__ p1,
                              u16* __restrict__ p2, u16* __restrict__ p3, int I) {
    int o = blockIdx.x;
    const int KD = 4 * I;
    const float* wr = w + (size_t)o * KD;
    for (int i = threadIdx.x; i < I; i += 256) {
        float4 v = *reinterpret_cast<const float4*>(&wr[i * 4]);
        float vals[4] = {v.x, v.y, v.z, v.w};
#pragma unroll
        for (int kcv = 0; kcv < 4; kcv++) {
            float f = vals[kcv];
            u16 h1 = f2bf(f); float r = f - bf2f(h1);
            u16 h2 = f2bf(r); r -= bf2f(h2);
            u16 h3 = f2bf(r);
            size_t idx = (size_t)o * KD + kcv * I + i;
            p1[idx] = h1; p2[idx] = h2; p3[idx] = h3;
        }
    }
}

// ---------------------------------------------------------------------------
// Generic 2D transpose: in (R, C) -> out (C, R).  Grid: (C/32, R/32), 256 thr.
// ---------------------------------------------------------------------------
__global__ void transpose2d(const float* __restrict__ in, float* __restrict__ out,
                            int R, int C) {
    __shared__ float tile[32][33];
    int c0 = blockIdx.x * 32, r0 = blockIdx.y * 32;
    int tx = threadIdx.x & 31, ty = threadIdx.x >> 5;
#pragma unroll
    for (int q = 0; q < 4; q++) {
        int r = ty + q * 8;
        tile[r][tx] = in[(size_t)(r0 + r) * C + (c0 + tx)];
    }
    __syncthreads();
#pragma unroll
    for (int q = 0; q < 4; q++) {
        int r = ty + q * 8;
        out[(size_t)(c0 + r) * R + (r0 + tx)] = tile[tx][r];
    }
}

__global__ void cnorm_kernel(const float* __restrict__ cb, float* __restrict__ cn) {
    int w = threadIdx.x >> 6, lane = threadIdx.x & 63;
    int row = blockIdx.x * 4 + w;
    float4 v = *reinterpret_cast<const float4*>(&cb[(size_t)row * 256 + lane * 4]);
    float s = v.x * v.x + v.y * v.y + v.z * v.z + v.w * v.w;
#pragma unroll
    for (int off = 32; off; off >>= 1) s += __shfl_xor(s, off);
    if (lane == 0) cn[row] = s;
}

// ---------------------------------------------------------------------------
// Conv1d(k=4,s=2,p=1) as bf16x3 MFMA GEMM.
// out[m, o] = sum_k x[b, 2t-1+kcv, i] * w[o][i][kcv],  m = b*1024 + t.
// A (activations) split on the fly into 3 bf16 planes in LDS (kg-major
// [4][128][8] per plane); B staged from pre-split transposed weight planes
// via global_load_lds.  6 MFMAs per fragment pair: a1b1,a1b2,a2b1,a1b3,a3b1,a2b2.
// Block: 256 thr (4 waves), tile 128x128, BK=32; wave quadrant 64x64 (4x4 frags).
// ---------------------------------------------------------------------------
__global__ __launch_bounds__(256, 3)
void conv_mfma(const float* __restrict__ x,
               const u16* __restrict__ wt1, const u16* __restrict__ wt2,
               const u16* __restrict__ wt3,
               const float* __restrict__ bias, float* __restrict__ out,
               int I, int O) {
    __shared__ u16 lds[24576];            // A: 3*4096 u16, B: 3*4096 u16 (48 KB)
    u16* As = lds;
    u16* Bs = lds + 12288;

    const int tid = threadIdx.x;
    const int wid = tid >> 6, lane = tid & 63;
    const int m0 = blockIdx.x * TM, n0 = blockIdx.y * TN;
    const int b = m0 >> 10, t0 = m0 & 1023;
    const float* xb = x + (size_t)b * 2048 * I;
    const int KD = 4 * I;
    const int wr = (wid >> 1) * 64, wc = (wid & 1) * 64;

    // A reg-stage mapping: thread -> row ar (0..127), col-half ah (0 or 16)
    const int ar = tid >> 1, ah = (tid & 1) * 16;
    // fragment lane mapping
    const int fl_row = lane & 15, fl_kg = lane >> 4;
    const int fkg = fl_kg * 1024;

    const u16* wts[3] = {wt1, wt2, wt3};

    f32x4 acc[4][4];
#pragma unroll
    for (int i = 0; i < 4; i++)
#pragma unroll
        for (int j = 0; j < 4; j++) acc[i][j] = (f32x4){0.f, 0.f, 0.f, 0.f};

    int kcv = 0, i0 = 0;
    for (int kt = 0; kt < KD; kt += TK) {
        // ---- B tiles: 24 x 1KB global_load_lds (6 per wave)
#pragma unroll
        for (int j = 0; j < 6; j++) {
            int ii = wid * 6 + j;
            int p = ii >> 3, i8 = ii & 7;
            int kg = i8 >> 1;
            int rowb = ((i8 & 1) << 6) + lane;
            gload_lds16(wts[p] + (size_t)(n0 + rowb) * KD + kt + kg * 8,
                        &Bs[p * 4096 + i8 * 512]);
        }
        // ---- A tile: load f32, split to 3 bf16 planes, kg-major LDS
        {
            int s = 2 * (t0 + ar) - 1 + kcv;
            bool ok = (s >= 0 && s < 2048);
            const float* src = xb + (size_t)s * I + i0 + ah;
#pragma unroll
            for (int q = 0; q < 4; q++) {
                float4 v = make_float4(0.f, 0.f, 0.f, 0.f);
                if (ok) v = *reinterpret_cast<const float4*>(src + q * 4);
                ushort4 h1, h2, h3;
                float f, r;
                f = v.x; h1.x = f2bf(f); r = f - bf2f(h1.x); h2.x = f2bf(r); r -= bf2f(h2.x); h3.x = f2bf(r);
                f = v.y; h1.y = f2bf(f); r = f - bf2f(h1.y); h2.y = f2bf(r); r -= bf2f(h2.y); h3.y = f2bf(r);
                f = v.z; h1.z = f2bf(f); r = f - bf2f(h1.z); h2.z = f2bf(r); r -= bf2f(h2.z); h3.z = f2bf(r);
                f = v.w; h1.w = f2bf(f); r = f - bf2f(h1.w); h2.w = f2bf(r); r -= bf2f(h2.w); h3.w = f2bf(r);
                int cc = ah + q * 4;
                int kg = cc >> 3, sub = (cc >> 2) & 1;
                int idx = kg * 1024 + ar * 8 + sub * 4;
                *reinterpret_cast<ushort4*>(&As[idx])        = h1;
                *reinterpret_cast<ushort4*>(&As[4096 + idx]) = h2;
                *reinterpret_cast<ushort4*>(&As[8192 + idx]) = h3;
            }
        }
        __syncthreads();
        // ---- fragments + 96 MFMAs
        bf16x8 bfr[3][4];
#pragma unroll
        for (int p = 0; p < 3; p++)
#pragma unroll
            for (int fn = 0; fn < 4; fn++)
                bfr[p][fn] = *reinterpret_cast<const bf16x8*>(
                    &Bs[p * 4096 + fkg + (wc + fn * 16 + fl_row) * 8]);
#pragma unroll
        for (int fm = 0; fm < 4; fm++) {
            int aidx = fkg + (wr + fm * 16 + fl_row) * 8;
            bf16x8 a1 = *reinterpret_cast<const bf16x8*>(&As[aidx]);
            bf16x8 a2 = *reinterpret_cast<const bf16x8*>(&As[4096 + aidx]);
            bf16x8 a3 = *reinterpret_cast<const bf16x8*>(&As[8192 + aidx]);
#pragma unroll
            for (int fn = 0; fn < 4; fn++) {
                f32x4 c = acc[fm][fn];
                c = __builtin_amdgcn_mfma_f32_16x16x32_bf16(a1, bfr[0][fn], c, 0, 0, 0);
                c = __builtin_amdgcn_mfma_f32_16x16x32_bf16(a1, bfr[1][fn], c, 0, 0, 0);
                c = __builtin_amdgcn_mfma_f32_16x16x32_bf16(a2, bfr[0][fn], c, 0, 0, 0);
                c = __builtin_amdgcn_mfma_f32_16x16x32_bf16(a1, bfr[2][fn], c, 0, 0, 0);
                c = __builtin_amdgcn_mfma_f32_16x16x32_bf16(a3, bfr[0][fn], c, 0, 0, 0);
                c = __builtin_amdgcn_mfma_f32_16x16x32_bf16(a2, bfr[1][fn], c, 0, 0, 0);
                acc[fm][fn] = c;
            }
        }
        __syncthreads();
        i0 += TK;
        if (i0 == I) { i0 = 0; kcv++; }
    }
    // ---- epilogue: C/D layout col=lane&15, row=(lane>>4)*4+j
#pragma unroll
    for (int fm = 0; fm < 4; fm++) {
        int row0 = m0 + wr + fm * 16 + fl_kg * 4;
#pragma unroll
        for (int fn = 0; fn < 4; fn++) {
            int col = n0 + wc + fn * 16 + fl_row;
            float bv = bias[col];
#pragma unroll
            for (int j = 0; j < 4; j++)
                out[(size_t)(row0 + j) * O + col] = acc[fm][fn][j] + bv;
        }
    }
}

// ---------------------------------------------------------------------------
// Projection: z_e[m, d] = sum_c concat[m, c] * wtP[c, d] + proj_b[d]   (f32)
// ---------------------------------------------------------------------------
__global__ __launch_bounds__(256)
void proj_gemm(const float* __restrict__ cA, const float* __restrict__ cB,
               const float* __restrict__ mu, const float* __restrict__ wt,
               const float* __restrict__ bias, float* __restrict__ out) {
    __shared__ float As[TK][TM + 4];
    __shared__ float Bs[TK][TN];
    const int tid = threadIdx.x;
    const int tx = tid & 15, ty = tid >> 4;
    const int m0 = blockIdx.x * TM;
    const int n0 = blockIdx.y * TN;
    const int O = 256;

    float acc[8][8];
#pragma unroll
    for (int i = 0; i < 8; i++)
#pragma unroll
        for (int j = 0; j < 8; j++) acc[i][j] = 0.f;

    for (int kt = 0; kt < 3328; kt += TK) {
        const float* ap; int astr, coff;
        if (kt < 1280)      { ap = cA; astr = 1280; coff = kt; }
        else if (kt < 2304) { ap = cB; astr = 1024; coff = kt - 1280; }
        else                { ap = mu; astr = 1024; coff = kt - 2304; }
#pragma unroll
        for (int p = 0; p < 4; p++) {
            int g = tid + p * 256;
            int r = g >> 3, c4 = (g & 7) << 2;
            float4 v = *reinterpret_cast<const float4*>(&ap[(size_t)(m0 + r) * astr + coff + c4]);
            As[c4 + 0][r] = v.x; As[c4 + 1][r] = v.y;
            As[c4 + 2][r] = v.z; As[c4 + 3][r] = v.w;
        }
#pragma unroll
        for (int p = 0; p < 4; p++) {
            int g = tid + p * 256;
            int kk = g >> 5, c4 = (g & 31) << 2;
            *reinterpret_cast<float4*>(&Bs[kk][c4]) =
                *reinterpret_cast<const float4*>(&wt[(size_t)(kt + kk) * O + n0 + c4]);
        }
        __syncthreads();
#pragma unroll
        for (int kk = 0; kk < TK; kk++) {
            float a[8], bf[8];
            *reinterpret_cast<float4*>(&a[0])  = *reinterpret_cast<const float4*>(&As[kk][ty * 4]);
            *reinterpret_cast<float4*>(&a[4])  = *reinterpret_cast<const float4*>(&As[kk][64 + ty * 4]);
            *reinterpret_cast<float4*>(&bf[0]) = *reinterpret_cast<const float4*>(&Bs[kk][tx * 4]);
            *reinterpret_cast<float4*>(&bf[4]) = *reinterpret_cast<const float4*>(&Bs[kk][64 + tx * 4]);
#pragma unroll
            for (int i = 0; i < 8; i++)
#pragma unroll
                for (int j = 0; j < 8; j++)
                    acc[i][j] = fmaf(a[i], bf[j], acc[i][j]);
        }
        __syncthreads();
    }
#pragma unroll
    for (int i = 0; i < 8; i++) {
        int row = m0 + ((i < 4) ? (ty * 4 + i) : (64 + ty * 4 + i - 4));
#pragma unroll
        for (int h = 0; h < 2; h++) {
            int col = n0 + h * 64 + tx * 4;
            float4 bv = *reinterpret_cast<const float4*>(&bias[col]);
            float4 o;
            o.x = acc[i][h * 4 + 0] + bv.x;
            o.y = acc[i][h * 4 + 1] + bv.y;
            o.z = acc[i][h * 4 + 2] + bv.z;
            o.w = acc[i][h * 4 + 3] + bv.w;
            *reinterpret_cast<float4*>(&out[(size_t)row * 256 + col]) = o;
        }
    }
}

// ---------------------------------------------------------------------------
// VQ pass 1 (f32 dot + f64 compare), per (128-row, 128-code) tile.
// ---------------------------------------------------------------------------
__global__ __launch_bounds__(256)
void vq_gemm(const float* __restrict__ z, const float* __restrict__ cbT,
             const float* __restrict__ cn, double* __restrict__ pmin,
             int* __restrict__ pidx) {
    __shared__ __align__(16) char smem[(TK * (TM + 4) + TK * TN) * 4];
    float (*As)[TM + 4] = reinterpret_cast<float (*)[TM + 4]>(smem);
    float (*Bs)[TN]     = reinterpret_cast<float (*)[TN]>(smem + TK * (TM + 4) * 4);
    const int tid = threadIdx.x;
    const int tx = tid & 15, ty = tid >> 4;
    const int m0 = blockIdx.x * TM;
    const int n0 = blockIdx.y * TN;

    float acc[8][8];
#pragma unroll
    for (int i = 0; i < 8; i++)
#pragma unroll
        for (int j = 0; j < 8; j++) acc[i][j] = 0.f;

    for (int kt = 0; kt < 256; kt += TK) {
#pragma unroll
        for (int p = 0; p < 4; p++) {
            int g = tid + p * 256;
            int r = g >> 3, c4 = (g & 7) << 2;
            float4 v = *reinterpret_cast<const float4*>(&z[(size_t)(m0 + r) * 256 + kt + c4]);
            As[c4 + 0][r] = v.x; As[c4 + 1][r] = v.y;
            As[c4 + 2][r] = v.z; As[c4 + 3][r] = v.w;
        }
#pragma unroll
        for (int p = 0; p < 4; p++) {
            int g = tid + p * 256;
            int kk = g >> 5, c4 = (g & 31) << 2;
            *reinterpret_cast<float4*>(&Bs[kk][c4]) =
                *reinterpret_cast<const float4*>(&cbT[(size_t)(kt + kk) * 8192 + n0 + c4]);
        }
        __syncthreads();
#pragma unroll
        for (int kk = 0; kk < TK; kk++) {
            float a[8], bf[8];
            *reinterpret_cast<float4*>(&a[0])  = *reinterpret_cast<const float4*>(&As[kk][ty * 4]);
            *reinterpret_cast<float4*>(&a[4])  = *reinterpret_cast<const float4*>(&As[kk][64 + ty * 4]);
            *reinterpret_cast<float4*>(&bf[0]) = *reinterpret_cast<const float4*>(&Bs[kk][tx * 4]);
            *reinterpret_cast<float4*>(&bf[4]) = *reinterpret_cast<const float4*>(&Bs[kk][64 + tx * 4]);
#pragma unroll
            for (int i = 0; i < 8; i++)
#pragma unroll
                for (int j = 0; j < 8; j++)
                    acc[i][j] = fmaf(a[i], bf[j], acc[i][j]);
        }
        __syncthreads();
    }
    double (*red_d)[16] = reinterpret_cast<double (*)[16]>(smem);
    int    (*red_n)[16] = reinterpret_cast<int    (*)[16]>(smem + 128 * 16 * 8);
#pragma unroll
    for (int i = 0; i < 8; i++) {
        int rl = (i < 4) ? (ty * 4 + i) : (64 + ty * 4 + i - 4);
        double best = 1e300; int bestn = 0x7fffffff;
#pragma unroll
        for (int j = 0; j < 8; j++) {
            int gn = n0 + ((j < 4) ? (tx * 4 + j) : (64 + tx * 4 + j - 4));
            double d = (double)cn[gn] - 2.0 * (double)acc[i][j];
            if (d < best || (d == best && gn < bestn)) { best = d; bestn = gn; }
        }
        red_d[rl][tx] = best; red_n[rl][tx] = bestn;
    }
    __syncthreads();
    if (tid < 128) {
        double best = red_d[tid][0]; int bestn = red_n[tid][0];
        for (int xk = 1; xk < 16; xk++) {
            double d = red_d[tid][xk]; int n2 = red_n[tid][xk];
            if (d < best || (d == best && n2 < bestn)) { best = d; bestn = n2; }
        }
        size_t idx = (size_t)(m0 + tid) * 64 + blockIdx.y;
        pmin[idx] = best; pidx[idx] = bestn;
    }
}

__global__ void vq_finalize(const double* __restrict__ pmin, const int* __restrict__ pidx,
                            const float* __restrict__ z, const float* __restrict__ cb,
                            float* __restrict__ out, double* __restrict__ cpart) {
    int w = threadIdx.x >> 6, lane = threadIdx.x & 63;
    int m = blockIdx.x * 4 + w;
    double d = pmin[(size_t)m * 64 + lane];
    int n = pidx[(size_t)m * 64 + lane];
#pragma unroll
    for (int off = 32; off; off >>= 1) {
        double d2 = __shfl_xor(d, off);
        int n2 = __shfl_xor(n, off);
        if (d2 < d || (d2 == d && n2 < n)) { d = d2; n = n2; }
    }
    float4 cv = *reinterpret_cast<const float4*>(&cb[(size_t)n * 256 + lane * 4]);
    float4 zv = *reinterpret_cast<const float4*>(&z[(size_t)m * 256 + lane * 4]);
    *reinterpret_cast<float4*>(&out[(size_t)m * 256 + lane * 4]) = cv;
    float dx = zv.x - cv.x, dy = zv.y - cv.y, dz = zv.z - cv.z, dw = zv.w - cv.w;
    double s = (double)(dx * dx) + (double)(dy * dy) + (double)(dz * dz) + (double)(dw * dw);
#pragma unroll
    for (int off = 32; off; off >>= 1) s += __shfl_xor(s, off);
    if (lane == 0) {
        out[2097152 + m] = (float)n;
        cpart[m] = s;
    }
}

__global__ void vq_reduce(const double* __restrict__ cpart, float* __restrict__ out) {
    __shared__ double sm[256];
    double s = 0.0;
    for (int i = threadIdx.x; i < 8192; i += 256) s += cpart[i];
    sm[threadIdx.x] = s;
    __syncthreads();
    for (int off = 128; off; off >>= 1) {
        if ((int)threadIdx.x < off) sm[threadIdx.x] += sm[threadIdx.x + off];
        __syncthreads();
    }
    if (threadIdx.x == 0) out[2105344] = (float)(sm[0] / 2097152.0);
}

// ---------------------------------------------------------------------------
extern "C" void kernel_launch(void* const* d_in, const int* in_sizes, int n_in,
                              void* d_out, int out_size, void* d_ws, size_t ws_size,
                              hipStream_t stream) {
    (void)in_sizes; (void)n_in; (void)out_size; (void)ws_size;
    const float* whisper   = (const float*)d_in[0];
    const float* wavlm     = (const float*)d_in[1];
    const float* muq       = (const float*)d_in[2];
    const float* w_conv_w  = (const float*)d_in[3];
    const float* w_conv_b  = (const float*)d_in[4];
    const float* wl_conv_w = (const float*)d_in[5];
    const float* wl_conv_b = (const float*)d_in[6];
    const float* proj_w    = (const float*)d_in[7];
    const float* proj_b    = (const float*)d_in[8];
    const float* codebook  = (const float*)d_in[9];
    float* out = (float*)d_out;

    // workspace layout (~166 MB)
    u16* wtbA = (u16*)d_ws;                       // 3 * 1280*5120 u16
    u16* wtbB = wtbA + 3u * 1280 * 5120;          // 3 * 1024*4096 u16
    float* WtP   = (float*)(wtbB + 3u * 1024 * 4096);
    float* cbT   = WtP   + 851968;                // 256*8192
    float* cnorm = cbT   + 2097152;               // 8192
    float* convA = cnorm + 8192;                  // 8192*1280
    float* convB = convA + 10485760;              // 8192*1024
    float* z_e   = convB + 8388608;               // 8192*256
    double* pmin = (double*)(z_e + 2097152);      // 8192*64
    int*    pidx = (int*)(pmin + 524288);
    double* cpart= (double*)(pidx + 524288);

    split_weightT<<<1280, 256, 0, stream>>>(w_conv_w, wtbA, wtbA + 1280 * 5120,
                                            wtbA + 2u * 1280 * 5120, 1280);
    split_weightT<<<1024, 256, 0, stream>>>(wl_conv_w, wtbB, wtbB + 1024 * 4096,
                                            wtbB + 2u * 1024 * 4096, 1024);
    transpose2d<<<dim3(104, 8), 256, 0, stream>>>(proj_w, WtP, 256, 3328);
    transpose2d<<<dim3(8, 256), 256, 0, stream>>>(codebook, cbT, 8192, 256);
    cnorm_kernel<<<2048, 256, 0, stream>>>(codebook, cnorm);

    conv_mfma<<<dim3(64, 10), 256, 0, stream>>>(whisper, wtbA, wtbA + 1280 * 5120,
                                                wtbA + 2u * 1280 * 5120, w_conv_b,
                                                convA, 1280, 1280);
    conv_mfma<<<dim3(64, 8), 256, 0, stream>>>(wavlm, wtbB, wtbB + 1024 * 4096,
                                               wtbB + 2u * 1024 * 4096, wl_conv_b,
                                               convB, 1024, 1024);
    proj_gemm<<<dim3(64, 2), 256, 0, stream>>>(convA, convB, muq, WtP, proj_b, z_e);

    vq_gemm<<<dim3(64, 64), 256, 0, stream>>>(z_e, cbT, cnorm, pmin, pidx);
    vq_finalize<<<2048, 256, 0, stream>>>(pmin, pidx, z_e, codebook, out, cpart);
    vq_reduce<<<1, 256, 0, stream>>>(cpart, out);
}